// Round 11
// baseline (96.716 us; speedup 1.0000x reference)
//
#include <hip/hip_runtime.h>

// AbsolutePositionExtractor: features[b, s*4+{0..3}] =
//   [sin(rad_lat*2^s), cos(rad_lat*2^s), sin(rad_lon*2^s), cos(rad_lon*2^s)]
// rad = fl32(deg*fl32(pi/180)); scale_s = int32(2**s): s=31 -> -2^31 (negate),
// s>=32 -> 0 -> (0,1,0,1). mask+positions = zeros.
//
// R11: R10 persistent-grid + plain stores, single change: store CONTIGUITY.
// R10 issued 2 stores of 2x512B disjoint spans; here each store instruction
// covers one full 1 KB point-row: store1 = rowA identity-mapped (lanes 0-31
// computed, 32-63 CONST), store2 = rowB rotate-by-32 (lanes 32-63 computed at
// (l-32), lanes 0-31 CONST at (l+32)). Permuted-but-contiguous coalesces
// fully (address-based coalescer). Compute mapping/trig count unchanged.

typedef float f32x4 __attribute__((ext_vector_type(4)));

#define PTS 256        // points staged per batch (4 KB LDS)
#define NBLK 2048      // 8 blocks/CU * 256 CUs — fully resident

__global__ __launch_bounds__(256) void posfeat_kernel(const float* __restrict__ ll,
                                                      f32x4* __restrict__ out,
                                                      int B, long long n4) {
    const double QHI = 0x1.45F306DC9C883p-3;      // fl64(1/(2*pi))
    const float DEG2RAD = 0.017453292519943295f;  // fl32(pi/180), matches np/jax deg2rad
    const long long featUnits = (long long)B * 64;
    const f32x4 CONST4 = {0.f, 1.f, 0.f, 1.f};
    const f32x4 ZERO4 = {0.f, 0.f, 0.f, 0.f};

    __shared__ uint4 yfix[PTS];                   // (hi_lat, lo_lat, hi_lon, lo_lon)
    const int t = threadIdx.x;
    const int nbatch = (B + PTS - 1) / PTS;

    const int s = t & 31;                         // scale 0..31 (32..63 are constants)
    const int po = t >> 5;                        // point-slot within iteration (0..7)
    const unsigned sh = (32 - s) & 31;
    const int lane = t & 63;
    const int wv2 = (t >> 6) * 2;                 // wave id * 2: wave's even point-slot
    const bool lo = lane < 32;

    for (int batch = blockIdx.x; batch < nbatch; batch += gridDim.x) {
        const int p0 = batch * PTS;
        {   // stage: all 256 threads, one point each; f64 used ONLY here
            int b = p0 + t;
            float2 p = (b < B) ? reinterpret_cast<const float2*>(ll)[b]
                               : make_float2(0.f, 0.f);
            float rlat = p.x * DEG2RAD;           // single f32 mul — bit-identical to ref
            float rlon = p.y * DEG2RAD;
            double ya = (double)rlat * QHI; ya -= floor(ya);   // frac -> [0,1)
            double yb = (double)rlon * QHI; yb -= floor(yb);
            double sa = ya * 4294967296.0;
            unsigned ha = (unsigned)sa;
            unsigned la = (unsigned)((sa - (double)ha) * 4294967296.0);
            double sb = yb * 4294967296.0;
            unsigned hb = (unsigned)sb;
            unsigned lb = (unsigned)((sb - (double)hb) * 4294967296.0);
            yfix[t] = make_uint4(ha, la, hb, lb);
        }
        __syncthreads();

        #pragma unroll 4
        for (int i = 0; i < PTS / 8; ++i) {       // 32 iterations, 8 points each
            int pl = i * 8 + po;                  // this lane's point (A for lo, B for hi)
            uint4 Y = yfix[pl];                   // 2 distinct rows per wave (broadcast)
            // frac(y * 2^s) = top 32 bits of (Y << s): funnel shift
            unsigned ra_u = (Y.x << s) | ((s == 0) ? 0u : (Y.y >> sh));
            unsigned rb_u = (Y.z << s) | ((s == 0) ? 0u : (Y.w >> sh));
            float ra = (float)ra_u * 0x1.0p-32f;  // revolutions in [0,1)
            float rb = (float)rb_u * 0x1.0p-32f;
            if (s == 31) { ra = -ra; rb = -rb; }  // int32 wrap: 2**31 -> -2^31
            f32x4 o;
            o.x = __builtin_amdgcn_sinf(ra);      // v_sin_f32: sin(2*pi*x)
            o.y = __builtin_amdgcn_cosf(ra);
            o.z = __builtin_amdgcn_sinf(rb);
            o.w = __builtin_amdgcn_cosf(rb);

            int pA = i * 8 + wv2;                 // wave's two points: pA (lanes 0-31
            int pB = pA + 1;                      //   computed), pB (lanes 32-63 computed)
            f32x4 d1 = lo ? o : CONST4;           // row A: computed s<32, const s>=32
            f32x4 d2 = lo ? CONST4 : o;           // row B: const s>=32 (rotated), computed s<32
            long long u1 = ((long long)(p0 + pA) << 6) + lane;              // identity map
            long long u2 = ((long long)(p0 + pB) << 6) + ((lane + 32) & 63); // rotate-32 map
            if (p0 + pA < B) out[u1] = d1;        // contiguous 1 KB wave store
            if (p0 + pB < B) out[u2] = d2;        // contiguous 1 KB wave store (permuted)
        }
        __syncthreads();                          // LDS reuse guard for next batch
    }

    // zero epilogue: mask [B] + positions [2B] (6 MB), same dispatch
    const long long gstride = (long long)gridDim.x * 256;
    for (long long z = featUnits + (long long)blockIdx.x * 256 + t; z < n4; z += gstride)
        out[z] = ZERO4;
}

__global__ void tail_zero_kernel(float* __restrict__ z, int n) {
    int t = threadIdx.x;
    if (t < n) z[t] = 0.f;
}

extern "C" void kernel_launch(void* const* d_in, const int* in_sizes, int n_in,
                              void* d_out, int out_size, void* d_ws, size_t ws_size,
                              hipStream_t stream) {
    const float* ll = (const float*)d_in[0];
    float* out = (float*)d_out;
    int B = in_sizes[0] / 2;

    long long n4 = (long long)out_size >> 2;
    posfeat_kernel<<<NBLK, 256, 0, stream>>>(ll, (f32x4*)out, B, n4);

    int tail = out_size & 3;
    if (tail) {
        tail_zero_kernel<<<1, 64, 0, stream>>>(out + ((long long)out_size - tail), tail);
    }
}